// Round 15
// baseline (315.665 us; speedup 1.0000x reference)
//
#include <hip/hip_runtime.h>
#include <hip/hip_bf16.h>

typedef float f32x4 __attribute__((ext_vector_type(4)));
typedef __bf16 bf16x8 __attribute__((ext_vector_type(8)));
typedef unsigned short u16x4 __attribute__((ext_vector_type(4)));
typedef unsigned short u16x8 __attribute__((ext_vector_type(8)));

__device__ __forceinline__ unsigned short f2bf(float f) {
  union { float f; unsigned u; } x; x.f = f;
  unsigned r = x.u + 0x7FFFu + ((x.u >> 16) & 1u);
  return (unsigned short)(r >> 16);
}

__device__ __forceinline__ void gl16(const void* g, void* l) {
  __builtin_amdgcn_global_load_lds(
      (const __attribute__((address_space(1))) unsigned*)g,
      (__attribute__((address_space(3))) unsigned*)l, 16, 0, 0);
}

// ---------------- prep: W[k][n] f32 -> WT[n][k] bf16 (4 mats: q,k,v,o) ----
__global__ __launch_bounds__(256) void prep_wt(const float* __restrict__ Wq,
                                               const float* __restrict__ Wk,
                                               const float* __restrict__ Wv,
                                               const float* __restrict__ Wo,
                                               unsigned short* __restrict__ WT) {
  __shared__ unsigned short ts[64][65];
  const float* W = (blockIdx.z == 0) ? Wq : (blockIdx.z == 1) ? Wk
                   : (blockIdx.z == 2) ? Wv : Wo;
  const int t = threadIdx.x;
  const int kbase = blockIdx.y * 64;
  const int nbase = blockIdx.x * 64;
  for (int i = 0; i < 16; ++i) {
    int idx = i * 256 + t;
    int r = idx >> 6, c = idx & 63;
    ts[r][c] = f2bf(W[(size_t)(kbase + r) * 512 + nbase + c]);
  }
  __syncthreads();
  unsigned short* dst = WT + (size_t)blockIdx.z * 512 * 512;
  for (int i = 0; i < 16; ++i) {
    int idx = i * 256 + t;
    int nn = idx >> 6, kk = idx & 63;
    dst[(size_t)(nbase + nn) * 512 + kbase + kk] = ts[kk][nn];
  }
}

__global__ void prep_bias(const float* __restrict__ bq, const float* __restrict__ bk,
                          const float* __restrict__ bv, float* __restrict__ biasc) {
  int i = blockIdx.x * 256 + threadIdx.x;
  if (i < 512) biasc[i] = bq[i];
  else if (i < 1024) biasc[i] = bk[i - 512];
  else if (i < 1536) biasc[i] = bv[i - 1024];
}

// ---------------- QKV GEMM: C(bf16) = cvt(A_f32) @ BT^T + bias ------------
// A f32 [M][512] staged RAW via gl16 into LDS (no VGPR transit, no VALU);
// f32->bf16 conversion happens in the fragment read (2x ds_read_b128 +
// cvt_pk per frag). BK=32, 128x128 tile, 4 waves, 1 barrier/phase (R14
// skeleton), 48KB LDS -> 3 blocks/CU.
// A swizzle (128B f32 rows, 8 granules): LDS[r][g] = G[r][g^(r&7)]
// via inverse-swizzled src; read slot = q^(r&7). B path = R14 verbatim.
__global__ __launch_bounds__(256, 3) void gemm128_f32(
    const float* __restrict__ A, int lda,
    const unsigned short* __restrict__ BT,
    unsigned short* __restrict__ C, int ldc,
    const float* __restrict__ bias, int NB) {
  __shared__ alignas(16) unsigned short pool[24576];  // A f32 2x16KB | B 2x8KB
  const int t = threadIdx.x;
  const int lane = t & 63;
  const int w = t >> 6;
  const int wm = w >> 1, wn = w & 1;

  const int nwg = gridDim.x;
  const int cpx = nwg >> 3;
  const int wg = (blockIdx.x & 7) * cpx + (blockIdx.x >> 3);
  const int n0 = (wg % NB) * 128;
  const int m0 = (wg / NB) * 128;

  // A staging: 8 rows/gl16, granule lane&7 (16B), inverse-swizzled src col
  const int sgr8 = lane >> 3;
  const int sga = ((lane & 7) ^ sgr8) << 2;        // f32 offset
  const float* gAf = A + (size_t)(m0 + w * 32 + sgr8) * lda + sga;
  // B staging (R14): 16 rows/gl16, granule lane&3, swizzle slot=g^((r>>1)&3)
  const int sgr = lane >> 2;
  const int sgc = ((lane & 3) ^ ((lane >> 3) & 3)) << 3;
  const unsigned short* gB = BT + (size_t)(n0 + w * 32 + sgr) * 512 + sgc;

#define SAF(kt, b)                                                          \
  _Pragma("unroll") for (int u = 0; u < 4; ++u) {                           \
    gl16(gAf + (size_t)(u) * 8 * lda + (kt) * 32,                           \
         &pool[(b) * 8192 + (w * 32 + u * 8) * 64]);                        \
  }
#define SB(kt, b)                                                           \
  { const unsigned short* g_ = gB + (kt) * 32;                              \
    gl16(g_, &pool[16384 + (b) * 4096 + w * 1024]);                         \
    gl16(g_ + (size_t)16 * 512, &pool[16384 + (b) * 4096 + w * 1024 + 512]); }

  const int fr = lane & 15;
  const int fg = lane >> 4;
  const int bslot = (fg ^ ((fr >> 1) & 3)) << 3;
  const float* apf = reinterpret_cast<const float*>(pool);

  f32x4 acc[4][4];
#pragma unroll
  for (int i = 0; i < 4; ++i)
#pragma unroll
    for (int j = 0; j < 4; ++j) acc[i][j] = (f32x4){0.f, 0.f, 0.f, 0.f};
  bf16x8 afr[4], bfr[4];

  // prologue: tile 0 into buf 0
  SAF(0, 0) SB(0, 0)
  asm volatile("s_waitcnt vmcnt(0)" ::: "memory");
  __builtin_amdgcn_s_barrier();

#pragma unroll
  for (int kt = 0; kt < 16; ++kt) {
    const int b = kt & 1;
    if (kt < 15) { SAF(kt + 1, b ^ 1) SB(kt + 1, b ^ 1) }
    // A frags: f32 granules 2fg,2fg+1 at swizzled slots -> cvt to bf16x8
#pragma unroll
    for (int mi = 0; mi < 4; ++mi) {
      const int r = wm * 64 + mi * 16 + fr;
      const int s0 = ((2 * fg) ^ (fr & 7)) << 2;
      const int s1 = ((2 * fg + 1) ^ (fr & 7)) << 2;
      f32x4 lo = *reinterpret_cast<const f32x4*>(&apf[b * 4096 + r * 32 + s0]);
      f32x4 hi = *reinterpret_cast<const f32x4*>(&apf[b * 4096 + r * 32 + s1]);
      bf16x8 o;
#pragma unroll
      for (int j = 0; j < 4; ++j) {
        o[j] = (__bf16)lo[j];
        o[4 + j] = (__bf16)hi[j];
      }
      afr[mi] = o;
    }
#pragma unroll
    for (int ni = 0; ni < 4; ++ni)
      bfr[ni] = *reinterpret_cast<const bf16x8*>(
          &pool[16384 + b * 4096 + (wn * 64 + ni * 16 + fr) * 32 + bslot]);
    asm volatile("s_waitcnt lgkmcnt(0)" ::: "memory");
    __builtin_amdgcn_sched_barrier(0);
    __builtin_amdgcn_s_setprio(1);
#pragma unroll
    for (int mi = 0; mi < 4; ++mi)
#pragma unroll
      for (int ni = 0; ni < 4; ++ni)
        acc[mi][ni] = __builtin_amdgcn_mfma_f32_16x16x32_bf16(
            afr[mi], bfr[ni], acc[mi][ni], 0, 0, 0);
    __builtin_amdgcn_s_setprio(0);
    asm volatile("s_waitcnt vmcnt(0)" ::: "memory");
    __builtin_amdgcn_s_barrier();
  }
#undef SAF
#undef SB

  // ---- coalesced epilogue via LDS staging (R14-verified bf16 branch) ----
#pragma unroll
  for (int ni = 0; ni < 4; ++ni) {
    int cl = wn * 64 + ni * 16 + fr;
    float bc = bias[n0 + cl];
#pragma unroll
    for (int mi = 0; mi < 4; ++mi) {
      int rl = wm * 64 + mi * 16 + fg * 4;
#pragma unroll
      for (int r = 0; r < 4; ++r)
        pool[(rl + r) * 130 + cl] = f2bf(acc[mi][ni][r] + bc);
    }
  }
  __syncthreads();
#pragma unroll
  for (int it = 0; it < 8; ++it) {
    int idx = it * 256 + t;
    int row = idx >> 4, c8 = idx & 15;
    u16x8 v = *reinterpret_cast<const u16x8*>(&pool[row * 130 + c8 * 8]);
    *reinterpret_cast<u16x8*>(&C[(size_t)(m0 + row) * ldc + n0 + c8 * 8]) = v;
  }
}

// ---------------- 128x128 GEMM, BK=32 (R14-verified) ----------------------
// Used for the output projection (A = ctx bf16, C = f32).
template <typename CT>
__global__ __launch_bounds__(256, 4) void gemm128(
    const unsigned short* __restrict__ A, int lda,
    const unsigned short* __restrict__ BT,
    CT* __restrict__ C, int ldc,
    const float* __restrict__ bias, int NB) {
  __shared__ alignas(16) unsigned short pool[16640];  // 33280 B
  const int t = threadIdx.x;
  const int lane = t & 63;
  const int w = t >> 6;
  const int wm = w >> 1, wn = w & 1;

  const int nwg = gridDim.x;
  const int cpx = nwg >> 3;
  const int wg = (blockIdx.x & 7) * cpx + (blockIdx.x >> 3);
  const int n0 = (wg % NB) * 128;
  const int m0 = (wg / NB) * 128;

  const int sgr = lane >> 2;
  const int sgc = ((lane & 3) ^ ((lane >> 3) & 3)) << 3;
  const unsigned short* gA = A + (size_t)(m0 + w * 32 + sgr) * lda + sgc;
  const unsigned short* gB = BT + (size_t)(n0 + w * 32 + sgr) * 512 + sgc;
  const int lw = w * 1024;

#define SA(kt, b)                                                           \
  { const unsigned short* g_ = gA + (kt) * 32;                              \
    gl16(g_, &pool[(b) * 4096 + lw]);                                       \
    gl16(g_ + (size_t)16 * lda, &pool[(b) * 4096 + lw + 512]); }
#define SB(kt, b)                                                           \
  { const unsigned short* g_ = gB + (kt) * 32;                              \
    gl16(g_, &pool[8192 + (b) * 4096 + lw]);                                \
    gl16(g_ + (size_t)16 * 512, &pool[8192 + (b) * 4096 + lw + 512]); }

  const int fr = lane & 15;
  const int fg = lane >> 4;
  const int aslot = (fg ^ ((fr >> 1) & 3)) << 3;

  f32x4 acc[4][4];
#pragma unroll
  for (int i = 0; i < 4; ++i)
#pragma unroll
    for (int j = 0; j < 4; ++j) acc[i][j] = (f32x4){0.f, 0.f, 0.f, 0.f};
  bf16x8 afr[4], bfr[4];

  SA(0, 0) SB(0, 0)
  asm volatile("s_waitcnt vmcnt(0)" ::: "memory");
  __builtin_amdgcn_s_barrier();

#pragma unroll
  for (int kt = 0; kt < 16; ++kt) {
    const int b = kt & 1;
    if (kt < 15) { SA(kt + 1, b ^ 1) SB(kt + 1, b ^ 1) }
#pragma unroll
    for (int mi = 0; mi < 4; ++mi)
      afr[mi] = *reinterpret_cast<const bf16x8*>(
          &pool[b * 4096 + (wm * 64 + mi * 16 + fr) * 32 + aslot]);
#pragma unroll
    for (int ni = 0; ni < 4; ++ni)
      bfr[ni] = *reinterpret_cast<const bf16x8*>(
          &pool[8192 + b * 4096 + (wn * 64 + ni * 16 + fr) * 32 + aslot]);
    asm volatile("s_waitcnt lgkmcnt(0)" ::: "memory");
    __builtin_amdgcn_sched_barrier(0);
    __builtin_amdgcn_s_setprio(1);
#pragma unroll
    for (int mi = 0; mi < 4; ++mi)
#pragma unroll
      for (int ni = 0; ni < 4; ++ni)
        acc[mi][ni] = __builtin_amdgcn_mfma_f32_16x16x32_bf16(
            afr[mi], bfr[ni], acc[mi][ni], 0, 0, 0);
    __builtin_amdgcn_s_setprio(0);
    asm volatile("s_waitcnt vmcnt(0)" ::: "memory");
    __builtin_amdgcn_s_barrier();
  }
#undef SA
#undef SB

  if constexpr (sizeof(CT) == 2) {
#pragma unroll
    for (int ni = 0; ni < 4; ++ni) {
      int cl = wn * 64 + ni * 16 + fr;
      float bc = bias[n0 + cl];
#pragma unroll
      for (int mi = 0; mi < 4; ++mi) {
        int rl = wm * 64 + mi * 16 + fg * 4;
#pragma unroll
        for (int r = 0; r < 4; ++r)
          pool[(rl + r) * 130 + cl] = f2bf(acc[mi][ni][r] + bc);
      }
    }
    __syncthreads();
#pragma unroll
    for (int it = 0; it < 8; ++it) {
      int idx = it * 256 + t;
      int row = idx >> 4, c8 = idx & 15;
      u16x8 v = *reinterpret_cast<const u16x8*>(&pool[row * 130 + c8 * 8]);
      *reinterpret_cast<u16x8*>(&C[(size_t)(m0 + row) * ldc + n0 + c8 * 8]) = v;
    }
  } else {
    float* stf = reinterpret_cast<float*>(pool);
#pragma unroll
    for (int h = 0; h < 2; ++h) {
      if (wm == h) {
#pragma unroll
        for (int ni = 0; ni < 4; ++ni) {
          int cl = wn * 64 + ni * 16 + fr;
          float bc = bias[n0 + cl];
#pragma unroll
          for (int mi = 0; mi < 4; ++mi) {
            int rl = mi * 16 + fg * 4;
#pragma unroll
            for (int r = 0; r < 4; ++r)
              stf[(rl + r) * 130 + cl] = acc[mi][ni][r] + bc;
          }
        }
      }
      __syncthreads();
#pragma unroll
      for (int it = 0; it < 8; ++it) {
        int idx = it * 256 + t;
        int row = idx >> 5, c4 = idx & 31;
        f32x4 v = *reinterpret_cast<const f32x4*>(&stf[row * 130 + c4 * 4]);
        *reinterpret_cast<f32x4*>(
            &C[(size_t)(m0 + h * 64 + row) * ldc + n0 + c4 * 4]) = v;
      }
      __syncthreads();
    }
  }
}

// ---------------- MFMA attention, double-buffered head pipeline -----------
// (R11-verified.) Block = 256 thr owns 128 rows; wave does 2 windows.
// LDS: K 2x8192 | V 2x8192 | ps 1024 = 33792 shorts.
__global__ __launch_bounds__(256) void attn2(unsigned short* __restrict__ QKV) {
  __shared__ alignas(16) unsigned short sh[33792];
  const int VS = 16384, PS = 32768;
  const int t = threadIdx.x;
  const int lane = t & 63;
  const int w = t >> 6;
  const int fr = lane & 15, fg = lane >> 4, fx = lane & 7;
  const int sr = lane >> 3;
  const int sgx = ((lane & 7) ^ sr) << 3;
  const int sgl = (lane & 7) << 3;
  const size_t m0r = (size_t)blockIdx.x * 128;

#define SK2(h, b)                                                            \
  _Pragma("unroll") for (int u = 0; u < 4; ++u) {                            \
    const int r0 = u * 32 + w * 8;                                           \
    gl16(QKV + (m0r + r0 + sr) * 1536 + 512 + (h) * 64 + sgx,                \
         &sh[(b) * 8192 + r0 * 64]);                                         \
  }
#define SV2(h, b)                                                            \
  _Pragma("unroll") for (int u = 0; u < 4; ++u) {                            \
    const int r0 = u * 32 + w * 8;                                           \
    gl16(QKV + (m0r + r0 + sr) * 1536 + 1024 + (h) * 64 + sgl,               \
         &sh[VS + (b) * 8192 + r0 * 64]);                                    \
  }

  SK2(0, 0) SV2(0, 0)
  asm volatile("s_waitcnt vmcnt(0)" ::: "memory");
  __syncthreads();

  for (int h = 0; h < 8; ++h) {
    const int b = h & 1;
    u16x8 q[2][2];
#pragma unroll
    for (int ww = 0; ww < 2; ++ww) {
      const int wi = w * 2 + ww;
      const unsigned short* qrow = QKV + (m0r + wi * 16 + fr) * 1536 + h * 64;
      q[ww][0] = *reinterpret_cast<const u16x8*>(qrow + fg * 8);
      q[ww][1] = *reinterpret_cast<const u16x8*>(qrow + 32 + fg * 8);
    }
    if (h < 7) { SK2(h + 1, b ^ 1) SV2(h + 1, b ^ 1) }

#pragma unroll
    for (int ww = 0; ww < 2; ++ww) {
      const int wi = w * 2 + ww;
      f32x4 s = (f32x4){0.f, 0.f, 0.f, 0.f};
      {
        bf16x8 kf_ = *reinterpret_cast<const bf16x8*>(
            &sh[b * 8192 + (wi * 16 + fr) * 64 + ((fg ^ fx) << 3)]);
        s = __builtin_amdgcn_mfma_f32_16x16x32_bf16(
            kf_, __builtin_bit_cast(bf16x8, q[ww][0]), s, 0, 0, 0);
        kf_ = *reinterpret_cast<const bf16x8*>(
            &sh[b * 8192 + (wi * 16 + fr) * 64 + (((4 + fg) ^ fx) << 3)]);
        s = __builtin_amdgcn_mfma_f32_16x16x32_bf16(
            kf_, __builtin_bit_cast(bf16x8, q[ww][1]), s, 0, 0, 0);
      }
      u16x4 pfu;
#pragma unroll
      for (int r = 0; r < 4; ++r)
        pfu[r] = f2bf(1.0f / (1.0f + __expf(-s[r] * 0.125f)));
      *reinterpret_cast<u16x4*>(&sh[PS + w * 256 + fr * 16 + fg * 4]) = pfu;
      u16x8 pbu = (u16x8){0, 0, 0, 0, 0, 0, 0, 0};
      if (fg < 2)
        pbu = *reinterpret_cast<const u16x8*>(&sh[PS + w * 256 + fr * 16 + fg * 8]);
      bf16x8 pb = __builtin_bit_cast(bf16x8, pbu);
#pragma unroll
      for (int dc = 0; dc < 4; ++dc) {
        u16x8 vau;
#pragma unroll
        for (int j = 0; j < 8; ++j)
          vau[j] = sh[VS + b * 8192 + (wi * 16 + (fg & 1) * 8 + j) * 64 + dc * 16 + fr];
        f32x4 c = __builtin_amdgcn_mfma_f32_16x16x32_bf16(
            __builtin_bit_cast(bf16x8, vau), pb, (f32x4){0.f, 0.f, 0.f, 0.f},
            0, 0, 0);
        u16x4 o;
#pragma unroll
        for (int r = 0; r < 4; ++r) o[r] = f2bf(c[r]);
        *reinterpret_cast<u16x4*>(
            &QKV[(m0r + wi * 16 + fr) * 1536 + 1024 + h * 64 + dc * 16 + fg * 4]) = o;
      }
    }
    asm volatile("s_waitcnt vmcnt(8)" ::: "memory");
    __syncthreads();
  }
#undef SK2
#undef SV2
}

// --------------------------------------------------------------------------
extern "C" void kernel_launch(void* const* d_in, const int* in_sizes, int n_in,
                              void* d_out, int out_size, void* d_ws, size_t ws_size,
                              hipStream_t stream) {
  const float* x  = (const float*)d_in[0];
  const float* Wq = (const float*)d_in[1];
  const float* bq = (const float*)d_in[2];
  const float* Wk = (const float*)d_in[3];
  const float* bk = (const float*)d_in[4];
  const float* Wv = (const float*)d_in[5];
  const float* bv = (const float*)d_in[6];
  const float* Wo = (const float*)d_in[7];
  const float* bo = (const float*)d_in[8];
  float* out = (float*)d_out;

  const int M = 65536;
  char* ws = (char*)d_ws;
  unsigned short* WT = (unsigned short*)ws;                  // [2048][512] bf16
  float* biasc = (float*)(ws + (size_t)2048 * 512 * 2);      // [1536]
  const long long prep_bytes = (long long)2048 * 512 * 2 + 8192;

  prep_wt<<<dim3(8, 8, 4), 256, 0, stream>>>(Wq, Wk, Wv, Wo, WT);
  prep_bias<<<6, 256, 0, stream>>>(bq, bk, bv, biasc);

  // per-chunk: QKV rows*1536*2 = rows*3072 B (no Xb)
  long long avail = (long long)ws_size - prep_bytes;
  int chunk_rows = 65536;
  while (chunk_rows > 2048 && (long long)chunk_rows * 3072 > avail) chunk_rows >>= 1;
  const int nchunks = M / chunk_rows;

  unsigned short* QKV = (unsigned short*)(ws + prep_bytes);

  for (int c = 0; c < nchunks; ++c) {
    const size_t row0 = (size_t)c * chunk_rows;
    const int mt = chunk_rows / 128;
    gemm128_f32<<<mt * 12, 256, 0, stream>>>(
        x + row0 * 512, 512, WT, QKV, 1536, biasc, 12);
    attn2<<<chunk_rows / 128, 256, 0, stream>>>(QKV);
    gemm128<float><<<mt * 4, 256, 0, stream>>>(
        QKV + 1024, 1536, WT + (size_t)1536 * 512, out + row0 * 512, 512, bo, 4);
  }
}

// Round 16
// 297.637 us; speedup vs baseline: 1.0606x; 1.0606x over previous
//
#include <hip/hip_runtime.h>
#include <hip/hip_bf16.h>

typedef float f32x4 __attribute__((ext_vector_type(4)));
typedef __bf16 bf16x8 __attribute__((ext_vector_type(8)));
typedef unsigned short u16x4 __attribute__((ext_vector_type(4)));
typedef unsigned short u16x8 __attribute__((ext_vector_type(8)));

__device__ __forceinline__ unsigned short f2bf(float f) {
  union { float f; unsigned u; } x; x.f = f;
  unsigned r = x.u + 0x7FFFu + ((x.u >> 16) & 1u);
  return (unsigned short)(r >> 16);
}

__device__ __forceinline__ void gl16(const void* g, void* l) {
  __builtin_amdgcn_global_load_lds(
      (const __attribute__((address_space(1))) unsigned*)g,
      (__attribute__((address_space(3))) unsigned*)l, 16, 0, 0);
}

// ---------------- prep: W[k][n] f32 -> WT[n][k] bf16 (4 mats: q,k,v,o) ----
__global__ __launch_bounds__(256) void prep_wt(const float* __restrict__ Wq,
                                               const float* __restrict__ Wk,
                                               const float* __restrict__ Wv,
                                               const float* __restrict__ Wo,
                                               unsigned short* __restrict__ WT) {
  __shared__ unsigned short ts[64][65];
  const float* W = (blockIdx.z == 0) ? Wq : (blockIdx.z == 1) ? Wk
                   : (blockIdx.z == 2) ? Wv : Wo;
  const int t = threadIdx.x;
  const int kbase = blockIdx.y * 64;
  const int nbase = blockIdx.x * 64;
  for (int i = 0; i < 16; ++i) {
    int idx = i * 256 + t;
    int r = idx >> 6, c = idx & 63;
    ts[r][c] = f2bf(W[(size_t)(kbase + r) * 512 + nbase + c]);
  }
  __syncthreads();
  unsigned short* dst = WT + (size_t)blockIdx.z * 512 * 512;
  for (int i = 0; i < 16; ++i) {
    int idx = i * 256 + t;
    int nn = idx >> 6, kk = idx & 63;
    dst[(size_t)(nbase + nn) * 512 + kbase + kk] = ts[kk][nn];
  }
}

__global__ void prep_bias(const float* __restrict__ bq, const float* __restrict__ bk,
                          const float* __restrict__ bv, float* __restrict__ biasc) {
  int i = blockIdx.x * 256 + threadIdx.x;
  if (i < 512) biasc[i] = bq[i];
  else if (i < 1024) biasc[i] = bk[i - 512];
  else if (i < 1536) biasc[i] = bv[i - 1024];
}

// ---------------- convert X fp32 -> bf16 (streaming) ----------------------
__global__ __launch_bounds__(256) void convert_x(const float* __restrict__ x,
                                                 unsigned short* __restrict__ xb,
                                                 long long n8) {
  long long i = (long long)blockIdx.x * 256 + threadIdx.x;
  const long long stride = (long long)gridDim.x * 256;
  for (; i < n8; i += stride) {
    f32x4 a = *reinterpret_cast<const f32x4*>(&x[i * 8]);
    f32x4 b = *reinterpret_cast<const f32x4*>(&x[i * 8 + 4]);
    u16x8 o;
    o[0] = f2bf(a[0]); o[1] = f2bf(a[1]); o[2] = f2bf(a[2]); o[3] = f2bf(a[3]);
    o[4] = f2bf(b[0]); o[5] = f2bf(b[1]); o[6] = f2bf(b[2]); o[7] = f2bf(b[3]);
    *reinterpret_cast<u16x8*>(&xb[i * 8]) = o;
  }
}

// ---------------- 256x256 8-phase GEMM (R11-verified, 128us QKV) ----------
// A bf16 [M][lda], BT bf16 [N][512], K=512 (8 K-tiles of BK=64).
// 512 thr = 8 waves (2m x 4n). LDS pool: K-loop = 2dbuf x (A+B) swizzled;
// epilogue reuses pool for coalesced C staging.
template <typename CT>
__global__ __launch_bounds__(512, 2) void gemm256(
    const unsigned short* __restrict__ A, int lda,
    const unsigned short* __restrict__ BT,
    CT* __restrict__ C, int ldc,
    const float* __restrict__ bias, int NB) {
  __shared__ alignas(16) unsigned short pool[66048];  // 132096 B
  const int t = threadIdx.x;
  const int lane = t & 63;
  const int w = t >> 6;
  const int wm = w >> 2, wn = w & 3;

  const int nwg = gridDim.x;
  const int cpx = nwg >> 3;
  const int wg = (blockIdx.x & 7) * cpx + (blockIdx.x >> 3);
  const int n0 = (wg % NB) * 256;
  const int m0 = (wg / NB) * 256;

  const int sr = lane >> 3;
  const int sg = ((lane & 7) ^ sr) << 3;
  const unsigned short* gA = A + (size_t)(m0 + w * 8 + sr) * lda + sg;
  const unsigned short* gB = BT + (size_t)(n0 + w * 8 + sr) * 512 + sg;
  const int lw = w * 512;

#define STAGE_A(kt, h, b)                                                   \
  { const unsigned short* g_ = gA + (size_t)(h) * 128 * lda + (kt) * 64;    \
    unsigned short* l_ = &pool[(b) * 16384 + (h) * 8192 + lw];              \
    gl16(g_, l_); gl16(g_ + (size_t)64 * lda, l_ + 4096); }
#define STAGE_B(kt, h, b)                                                   \
  { const unsigned short* g_ = gB + (size_t)(h) * 128 * 512 + (kt) * 64;    \
    unsigned short* l_ = &pool[32768 + (b) * 16384 + (h) * 8192 + lw];      \
    gl16(g_, l_); gl16(g_ + (size_t)64 * 512, l_ + 4096); }

  const int fr = lane & 15;
  const int fg = lane >> 4;
  const int fx = lane & 7;
  auto readA = [&](int b, int mi, int kf) -> bf16x8 {
    return *reinterpret_cast<const bf16x8*>(
        &pool[(b) * 16384 + (wm * 128 + mi * 16 + fr) * 64 +
              ((((kf << 2) + fg) ^ fx) << 3)]);
  };
  auto readB = [&](int b, int ni, int kf) -> bf16x8 {
    return *reinterpret_cast<const bf16x8*>(
        &pool[32768 + (b) * 16384 + (wn * 64 + ni * 16 + fr) * 64 +
              ((((kf << 2) + fg) ^ fx) << 3)]);
  };

  f32x4 acc[8][4];
#pragma unroll
  for (int i = 0; i < 8; ++i)
#pragma unroll
    for (int j = 0; j < 4; ++j) acc[i][j] = (f32x4){0.f, 0.f, 0.f, 0.f};
  bf16x8 bfr[4][2];

#define PHASE(b, q, READB, STAGES, VM)                                       \
  {                                                                          \
    bf16x8 a0_ = readA(b, 2 * (q), 0), a1_ = readA(b, 2 * (q), 1);           \
    bf16x8 a2_ = readA(b, 2 * (q) + 1, 0), a3_ = readA(b, 2 * (q) + 1, 1);   \
    if (READB) {                                                             \
      _Pragma("unroll") for (int ni = 0; ni < 4; ++ni) {                     \
        bfr[ni][0] = readB(b, ni, 0);                                        \
        bfr[ni][1] = readB(b, ni, 1);                                        \
      }                                                                      \
    }                                                                        \
    STAGES;                                                                  \
    if ((VM) == 4) asm volatile("s_waitcnt vmcnt(4)" ::: "memory");          \
    if ((VM) == 0) asm volatile("s_waitcnt vmcnt(0)" ::: "memory");          \
    __builtin_amdgcn_s_barrier();                                            \
    asm volatile("s_waitcnt lgkmcnt(0)" ::: "memory");                       \
    __builtin_amdgcn_sched_barrier(0);                                       \
    __builtin_amdgcn_s_setprio(1);                                           \
    _Pragma("unroll") for (int ni = 0; ni < 4; ++ni) {                       \
      acc[2 * (q)][ni] = __builtin_amdgcn_mfma_f32_16x16x32_bf16(            \
          a0_, bfr[ni][0], acc[2 * (q)][ni], 0, 0, 0);                       \
      acc[2 * (q) + 1][ni] = __builtin_amdgcn_mfma_f32_16x16x32_bf16(        \
          a2_, bfr[ni][0], acc[2 * (q) + 1][ni], 0, 0, 0);                   \
    }                                                                        \
    _Pragma("unroll") for (int ni = 0; ni < 4; ++ni) {                       \
      acc[2 * (q)][ni] = __builtin_amdgcn_mfma_f32_16x16x32_bf16(            \
          a1_, bfr[ni][1], acc[2 * (q)][ni], 0, 0, 0);                       \
      acc[2 * (q) + 1][ni] = __builtin_amdgcn_mfma_f32_16x16x32_bf16(        \
          a3_, bfr[ni][1], acc[2 * (q) + 1][ni], 0, 0, 0);                   \
    }                                                                        \
    __builtin_amdgcn_s_setprio(0);                                           \
    __builtin_amdgcn_s_barrier();                                            \
  }

  STAGE_B(0, 0, 0); STAGE_B(0, 1, 0);
  STAGE_A(0, 0, 0); STAGE_A(0, 1, 0);
  STAGE_B(1, 0, 1); STAGE_B(1, 1, 1);
  asm volatile("s_waitcnt vmcnt(4)" ::: "memory");
  __builtin_amdgcn_s_barrier();

#pragma unroll
  for (int i = 0; i < 4; ++i) {
    const bool s2 = (i < 3);
    const int vmA = s2 ? 4 : 0;
    const int vmB = s2 ? 4 : 0;
    PHASE(0, 0, true,  { STAGE_A(2 * i + 1, 0, 1) }, -1);
    PHASE(0, 1, false, { STAGE_A(2 * i + 1, 1, 1) if (s2) STAGE_B(2 * i + 2, 0, 0) }, -1);
    PHASE(0, 2, false, { if (s2) STAGE_B(2 * i + 2, 1, 0) }, -1);
    PHASE(0, 3, false, {}, vmA);
    PHASE(1, 0, true,  { if (s2) STAGE_A(2 * i + 2, 0, 0) }, -1);
    PHASE(1, 1, false, { if (s2) STAGE_A(2 * i + 2, 1, 0) }, -1);
    PHASE(1, 2, false, { if (s2) STAGE_B(2 * i + 3, 0, 1) }, -1);
    PHASE(1, 3, false, { if (s2) STAGE_B(2 * i + 3, 1, 1) }, vmB);
  }
#undef PHASE
#undef STAGE_A
#undef STAGE_B

  // ---- coalesced epilogue via LDS staging (R4/R11-verified) ----
  __syncthreads();
  if constexpr (sizeof(CT) == 2) {
#pragma unroll
    for (int ni = 0; ni < 4; ++ni) {
      int cl = wn * 64 + ni * 16 + fr;
      float bc = bias[n0 + cl];
#pragma unroll
      for (int mi = 0; mi < 8; ++mi) {
        int rl = wm * 128 + mi * 16 + fg * 4;
#pragma unroll
        for (int r = 0; r < 4; ++r)
          pool[(rl + r) * 258 + cl] = f2bf(acc[mi][ni][r] + bc);
      }
    }
    __syncthreads();
#pragma unroll
    for (int it = 0; it < 16; ++it) {
      int idx = it * 512 + t;
      int row = idx >> 5, c8 = idx & 31;
      u16x8 v = *reinterpret_cast<const u16x8*>(&pool[row * 258 + c8 * 8]);
      *reinterpret_cast<u16x8*>(&C[(size_t)(m0 + row) * ldc + n0 + c8 * 8]) = v;
    }
  } else {
    float* stf = reinterpret_cast<float*>(pool);
#pragma unroll
    for (int h = 0; h < 2; ++h) {
      if (wm == h) {
#pragma unroll
        for (int ni = 0; ni < 4; ++ni) {
          int cl = wn * 64 + ni * 16 + fr;
          float bc = bias[n0 + cl];
#pragma unroll
          for (int mi = 0; mi < 8; ++mi) {
            int rl = mi * 16 + fg * 4;
#pragma unroll
            for (int r = 0; r < 4; ++r)
              stf[(rl + r) * 258 + cl] = acc[mi][ni][r] + bc;
          }
        }
      }
      __syncthreads();
#pragma unroll
      for (int it = 0; it < 16; ++it) {
        int idx = it * 512 + t;
        int row = idx >> 6, c4 = idx & 63;
        f32x4 v = *reinterpret_cast<const f32x4*>(&stf[row * 258 + c4 * 4]);
        *reinterpret_cast<f32x4*>(
            &C[(size_t)(m0 + h * 128 + row) * ldc + n0 + c4 * 4]) = v;
      }
      __syncthreads();
    }
  }
}

// ---------------- 128x128 GEMM, BK=32 (R14-verified) ----------------------
// Used for the output projection (A = ctx bf16, C = f32), 4 blocks/CU.
template <typename CT>
__global__ __launch_bounds__(256, 4) void gemm128(
    const unsigned short* __restrict__ A, int lda,
    const unsigned short* __restrict__ BT,
    CT* __restrict__ C, int ldc,
    const float* __restrict__ bias, int NB) {
  __shared__ alignas(16) unsigned short pool[16640];  // 33280 B
  const int t = threadIdx.x;
  const int lane = t & 63;
  const int w = t >> 6;
  const int wm = w >> 1, wn = w & 1;

  const int nwg = gridDim.x;
  const int cpx = nwg >> 3;
  const int wg = (blockIdx.x & 7) * cpx + (blockIdx.x >> 3);
  const int n0 = (wg % NB) * 128;
  const int m0 = (wg / NB) * 128;

  const int sgr = lane >> 2;
  const int sgc = ((lane & 3) ^ ((lane >> 3) & 3)) << 3;
  const unsigned short* gA = A + (size_t)(m0 + w * 32 + sgr) * lda + sgc;
  const unsigned short* gB = BT + (size_t)(n0 + w * 32 + sgr) * 512 + sgc;
  const int lw = w * 1024;

#define SA(kt, b)                                                           \
  { const unsigned short* g_ = gA + (kt) * 32;                              \
    gl16(g_, &pool[(b) * 4096 + lw]);                                       \
    gl16(g_ + (size_t)16 * lda, &pool[(b) * 4096 + lw + 512]); }
#define SB(kt, b)                                                           \
  { const unsigned short* g_ = gB + (kt) * 32;                              \
    gl16(g_, &pool[8192 + (b) * 4096 + lw]);                                \
    gl16(g_ + (size_t)16 * 512, &pool[8192 + (b) * 4096 + lw + 512]); }

  const int fr = lane & 15;
  const int fg = lane >> 4;
  const int aslot = (fg ^ ((fr >> 1) & 3)) << 3;

  f32x4 acc[4][4];
#pragma unroll
  for (int i = 0; i < 4; ++i)
#pragma unroll
    for (int j = 0; j < 4; ++j) acc[i][j] = (f32x4){0.f, 0.f, 0.f, 0.f};
  bf16x8 afr[4], bfr[4];

  SA(0, 0) SB(0, 0)
  asm volatile("s_waitcnt vmcnt(0)" ::: "memory");
  __builtin_amdgcn_s_barrier();

#pragma unroll
  for (int kt = 0; kt < 16; ++kt) {
    const int b = kt & 1;
    if (kt < 15) { SA(kt + 1, b ^ 1) SB(kt + 1, b ^ 1) }
#pragma unroll
    for (int mi = 0; mi < 4; ++mi)
      afr[mi] = *reinterpret_cast<const bf16x8*>(
          &pool[b * 4096 + (wm * 64 + mi * 16 + fr) * 32 + aslot]);
#pragma unroll
    for (int ni = 0; ni < 4; ++ni)
      bfr[ni] = *reinterpret_cast<const bf16x8*>(
          &pool[8192 + b * 4096 + (wn * 64 + ni * 16 + fr) * 32 + aslot]);
    asm volatile("s_waitcnt lgkmcnt(0)" ::: "memory");
    __builtin_amdgcn_sched_barrier(0);
    __builtin_amdgcn_s_setprio(1);
#pragma unroll
    for (int mi = 0; mi < 4; ++mi)
#pragma unroll
      for (int ni = 0; ni < 4; ++ni)
        acc[mi][ni] = __builtin_amdgcn_mfma_f32_16x16x32_bf16(
            afr[mi], bfr[ni], acc[mi][ni], 0, 0, 0);
    __builtin_amdgcn_s_setprio(0);
    asm volatile("s_waitcnt vmcnt(0)" ::: "memory");
    __builtin_amdgcn_s_barrier();
  }
#undef SA
#undef SB

  if constexpr (sizeof(CT) == 2) {
#pragma unroll
    for (int ni = 0; ni < 4; ++ni) {
      int cl = wn * 64 + ni * 16 + fr;
      float bc = bias[n0 + cl];
#pragma unroll
      for (int mi = 0; mi < 4; ++mi) {
        int rl = wm * 64 + mi * 16 + fg * 4;
#pragma unroll
        for (int r = 0; r < 4; ++r)
          pool[(rl + r) * 130 + cl] = f2bf(acc[mi][ni][r] + bc);
      }
    }
    __syncthreads();
#pragma unroll
    for (int it = 0; it < 8; ++it) {
      int idx = it * 256 + t;
      int row = idx >> 4, c8 = idx & 15;
      u16x8 v = *reinterpret_cast<const u16x8*>(&pool[row * 130 + c8 * 8]);
      *reinterpret_cast<u16x8*>(&C[(size_t)(m0 + row) * ldc + n0 + c8 * 8]) = v;
    }
  } else {
    float* stf = reinterpret_cast<float*>(pool);
#pragma unroll
    for (int h = 0; h < 2; ++h) {
      if (wm == h) {
#pragma unroll
        for (int ni = 0; ni < 4; ++ni) {
          int cl = wn * 64 + ni * 16 + fr;
          float bc = bias[n0 + cl];
#pragma unroll
          for (int mi = 0; mi < 4; ++mi) {
            int rl = mi * 16 + fg * 4;
#pragma unroll
            for (int r = 0; r < 4; ++r)
              stf[(rl + r) * 130 + cl] = acc[mi][ni][r] + bc;
          }
        }
      }
      __syncthreads();
#pragma unroll
      for (int it = 0; it < 8; ++it) {
        int idx = it * 256 + t;
        int row = idx >> 5, c4 = idx & 31;
        f32x4 v = *reinterpret_cast<const f32x4*>(&stf[row * 130 + c4 * 4]);
        *reinterpret_cast<f32x4*>(
            &C[(size_t)(m0 + h * 64 + row) * ldc + n0 + c4 * 4]) = v;
      }
      __syncthreads();
    }
  }
}

// ---------------- MFMA attention, double-buffered head pipeline -----------
// (R11-verified.) Block = 256 thr owns 128 rows; wave does 2 windows.
// LDS: K 2x8192 | V 2x8192 | ps 1024 = 33792 shorts.
__global__ __launch_bounds__(256) void attn2(unsigned short* __restrict__ QKV) {
  __shared__ alignas(16) unsigned short sh[33792];
  const int VS = 16384, PS = 32768;
  const int t = threadIdx.x;
  const int lane = t & 63;
  const int w = t >> 6;
  const int fr = lane & 15, fg = lane >> 4, fx = lane & 7;
  const int sr = lane >> 3;
  const int sgx = ((lane & 7) ^ sr) << 3;
  const int sgl = (lane & 7) << 3;
  const size_t m0r = (size_t)blockIdx.x * 128;

#define SK2(h, b)                                                            \
  _Pragma("unroll") for (int u = 0; u < 4; ++u) {                            \
    const int r0 = u * 32 + w * 8;                                           \
    gl16(QKV + (m0r + r0 + sr) * 1536 + 512 + (h) * 64 + sgx,                \
         &sh[(b) * 8192 + r0 * 64]);                                         \
  }
#define SV2(h, b)                                                            \
  _Pragma("unroll") for (int u = 0; u < 4; ++u) {                            \
    const int r0 = u * 32 + w * 8;                                           \
    gl16(QKV + (m0r + r0 + sr) * 1536 + 1024 + (h) * 64 + sgl,               \
         &sh[VS + (b) * 8192 + r0 * 64]);                                    \
  }

  SK2(0, 0) SV2(0, 0)
  asm volatile("s_waitcnt vmcnt(0)" ::: "memory");
  __syncthreads();

  for (int h = 0; h < 8; ++h) {
    const int b = h & 1;
    u16x8 q[2][2];
#pragma unroll
    for (int ww = 0; ww < 2; ++ww) {
      const int wi = w * 2 + ww;
      const unsigned short* qrow = QKV + (m0r + wi * 16 + fr) * 1536 + h * 64;
      q[ww][0] = *reinterpret_cast<const u16x8*>(qrow + fg * 8);
      q[ww][1] = *reinterpret_cast<const u16x8*>(qrow + 32 + fg * 8);
    }
    if (h < 7) { SK2(h + 1, b ^ 1) SV2(h + 1, b ^ 1) }

#pragma unroll
    for (int ww = 0; ww < 2; ++ww) {
      const int wi = w * 2 + ww;
      f32x4 s = (f32x4){0.f, 0.f, 0.f, 0.f};
      {
        bf16x8 kf_ = *reinterpret_cast<const bf16x8*>(
            &sh[b * 8192 + (wi * 16 + fr) * 64 + ((fg ^ fx) << 3)]);
        s = __builtin_amdgcn_mfma_f32_16x16x32_bf16(
            kf_, __builtin_bit_cast(bf16x8, q[ww][0]), s, 0, 0, 0);
        kf_ = *reinterpret_cast<const bf16x8*>(
            &sh[b * 8192 + (wi * 16 + fr) * 64 + (((4 + fg) ^ fx) << 3)]);
        s = __builtin_amdgcn_mfma_f32_16x16x32_bf16(
            kf_, __builtin_bit_cast(bf16x8, q[ww][1]), s, 0, 0, 0);
      }
      u16x4 pfu;
#pragma unroll
      for (int r = 0; r < 4; ++r)
        pfu[r] = f2bf(1.0f / (1.0f + __expf(-s[r] * 0.125f)));
      *reinterpret_cast<u16x4*>(&sh[PS + w * 256 + fr * 16 + fg * 4]) = pfu;
      u16x8 pbu = (u16x8){0, 0, 0, 0, 0, 0, 0, 0};
      if (fg < 2)
        pbu = *reinterpret_cast<const u16x8*>(&sh[PS + w * 256 + fr * 16 + fg * 8]);
      bf16x8 pb = __builtin_bit_cast(bf16x8, pbu);
#pragma unroll
      for (int dc = 0; dc < 4; ++dc) {
        u16x8 vau;
#pragma unroll
        for (int j = 0; j < 8; ++j)
          vau[j] = sh[VS + b * 8192 + (wi * 16 + (fg & 1) * 8 + j) * 64 + dc * 16 + fr];
        f32x4 c = __builtin_amdgcn_mfma_f32_16x16x32_bf16(
            __builtin_bit_cast(bf16x8, vau), pb, (f32x4){0.f, 0.f, 0.f, 0.f},
            0, 0, 0);
        u16x4 o;
#pragma unroll
        for (int r = 0; r < 4; ++r) o[r] = f2bf(c[r]);
        *reinterpret_cast<u16x4*>(
            &QKV[(m0r + wi * 16 + fr) * 1536 + 1024 + h * 64 + dc * 16 + fg * 4]) = o;
      }
    }
    asm volatile("s_waitcnt vmcnt(8)" ::: "memory");
    __syncthreads();
  }
#undef SK2
#undef SV2
}

// --------------------------------------------------------------------------
extern "C" void kernel_launch(void* const* d_in, const int* in_sizes, int n_in,
                              void* d_out, int out_size, void* d_ws, size_t ws_size,
                              hipStream_t stream) {
  const float* x  = (const float*)d_in[0];
  const float* Wq = (const float*)d_in[1];
  const float* bq = (const float*)d_in[2];
  const float* Wk = (const float*)d_in[3];
  const float* bk = (const float*)d_in[4];
  const float* Wv = (const float*)d_in[5];
  const float* bv = (const float*)d_in[6];
  const float* Wo = (const float*)d_in[7];
  const float* bo = (const float*)d_in[8];
  float* out = (float*)d_out;

  const int M = 65536;
  char* ws = (char*)d_ws;
  unsigned short* WT = (unsigned short*)ws;                  // [2048][512] bf16
  float* biasc = (float*)(ws + (size_t)2048 * 512 * 2);      // [1536]
  const long long prep_bytes = (long long)2048 * 512 * 2 + 8192;

  prep_wt<<<dim3(8, 8, 4), 256, 0, stream>>>(Wq, Wk, Wv, Wo, WT);
  prep_bias<<<6, 256, 0, stream>>>(bq, bk, bv, biasc);

  // per-chunk: Xb rows*512*2 + QKV rows*1536*2 = rows*4096 B
  long long avail = (long long)ws_size - prep_bytes;
  int chunk_rows = 65536;
  while (chunk_rows > 2048 && (long long)chunk_rows * 4096 > avail) chunk_rows >>= 1;
  const int nchunks = M / chunk_rows;

  unsigned short* Xb  = (unsigned short*)(ws + prep_bytes);
  unsigned short* QKV = Xb + (size_t)chunk_rows * 512;

  for (int c = 0; c < nchunks; ++c) {
    const size_t row0 = (size_t)c * chunk_rows;
    convert_x<<<2048, 256, 0, stream>>>(x + row0 * 512, Xb,
                                        (long long)chunk_rows * 64);
    gemm256<unsigned short><<<(chunk_rows / 256) * 6, 512, 0, stream>>>(
        Xb, 512, WT, QKV, 1536, biasc, 6);
    attn2<<<chunk_rows / 128, 256, 0, stream>>>(QKV);
    gemm128<float><<<(chunk_rows / 128) * 4, 256, 0, stream>>>(
        QKV + 1024, 1536, WT + (size_t)1536 * 512, out + row0 * 512, 512, bo, 4);
  }
}

// Round 17
// 292.996 us; speedup vs baseline: 1.0774x; 1.0158x over previous
//
#include <hip/hip_runtime.h>
#include <hip/hip_bf16.h>

typedef float f32x4 __attribute__((ext_vector_type(4)));
typedef __bf16 bf16x8 __attribute__((ext_vector_type(8)));
typedef unsigned short u16x4 __attribute__((ext_vector_type(4)));
typedef unsigned short u16x8 __attribute__((ext_vector_type(8)));

__device__ __forceinline__ unsigned short f2bf(float f) {
  union { float f; unsigned u; } x; x.f = f;
  unsigned r = x.u + 0x7FFFu + ((x.u >> 16) & 1u);
  return (unsigned short)(r >> 16);
}

__device__ __forceinline__ void gl16(const void* g, void* l) {
  __builtin_amdgcn_global_load_lds(
      (const __attribute__((address_space(1))) unsigned*)g,
      (__attribute__((address_space(3))) unsigned*)l, 16, 0, 0);
}

// ---------------- prep: W[k][n] f32 -> WT[n][k] bf16 (4 mats: q,k,v,o) ----
__global__ __launch_bounds__(256) void prep_wt(const float* __restrict__ Wq,
                                               const float* __restrict__ Wk,
                                               const float* __restrict__ Wv,
                                               const float* __restrict__ Wo,
                                               unsigned short* __restrict__ WT) {
  __shared__ unsigned short ts[64][65];
  const float* W = (blockIdx.z == 0) ? Wq : (blockIdx.z == 1) ? Wk
                   : (blockIdx.z == 2) ? Wv : Wo;
  const int t = threadIdx.x;
  const int kbase = blockIdx.y * 64;
  const int nbase = blockIdx.x * 64;
  for (int i = 0; i < 16; ++i) {
    int idx = i * 256 + t;
    int r = idx >> 6, c = idx & 63;
    ts[r][c] = f2bf(W[(size_t)(kbase + r) * 512 + nbase + c]);
  }
  __syncthreads();
  unsigned short* dst = WT + (size_t)blockIdx.z * 512 * 512;
  for (int i = 0; i < 16; ++i) {
    int idx = i * 256 + t;
    int nn = idx >> 6, kk = idx & 63;
    dst[(size_t)(nbase + nn) * 512 + kbase + kk] = ts[kk][nn];
  }
}

__global__ void prep_bias(const float* __restrict__ bq, const float* __restrict__ bk,
                          const float* __restrict__ bv, float* __restrict__ biasc) {
  int i = blockIdx.x * 256 + threadIdx.x;
  if (i < 512) biasc[i] = bq[i];
  else if (i < 1024) biasc[i] = bk[i - 512];
  else if (i < 1536) biasc[i] = bv[i - 1024];
}

// ---------------- convert X fp32 -> bf16 (streaming) ----------------------
__global__ __launch_bounds__(256) void convert_x(const float* __restrict__ x,
                                                 unsigned short* __restrict__ xb,
                                                 long long n8) {
  long long i = (long long)blockIdx.x * 256 + threadIdx.x;
  const long long stride = (long long)gridDim.x * 256;
  for (; i < n8; i += stride) {
    f32x4 a = *reinterpret_cast<const f32x4*>(&x[i * 8]);
    f32x4 b = *reinterpret_cast<const f32x4*>(&x[i * 8 + 4]);
    u16x8 o;
    o[0] = f2bf(a[0]); o[1] = f2bf(a[1]); o[2] = f2bf(a[2]); o[3] = f2bf(a[3]);
    o[4] = f2bf(b[0]); o[5] = f2bf(b[1]); o[6] = f2bf(b[2]); o[7] = f2bf(b[3]);
    *reinterpret_cast<u16x8*>(&xb[i * 8]) = o;
  }
}

// ---------------- 256x256 8-phase GEMM (R11-verified, 128us QKV) ----------
// A bf16 [M][lda], BT bf16 [N][512], K=512 (8 K-tiles of BK=64).
// 512 thr = 8 waves (2m x 4n). LDS pool: K-loop = 2dbuf x (A+B) swizzled;
// epilogue reuses pool for coalesced C staging.
template <typename CT>
__global__ __launch_bounds__(512, 2) void gemm256(
    const unsigned short* __restrict__ A, int lda,
    const unsigned short* __restrict__ BT,
    CT* __restrict__ C, int ldc,
    const float* __restrict__ bias, int NB) {
  __shared__ alignas(16) unsigned short pool[66048];  // 132096 B
  const int t = threadIdx.x;
  const int lane = t & 63;
  const int w = t >> 6;
  const int wm = w >> 2, wn = w & 3;

  const int nwg = gridDim.x;
  const int cpx = nwg >> 3;
  const int wg = (blockIdx.x & 7) * cpx + (blockIdx.x >> 3);
  const int n0 = (wg % NB) * 256;
  const int m0 = (wg / NB) * 256;

  const int sr = lane >> 3;
  const int sg = ((lane & 7) ^ sr) << 3;
  const unsigned short* gA = A + (size_t)(m0 + w * 8 + sr) * lda + sg;
  const unsigned short* gB = BT + (size_t)(n0 + w * 8 + sr) * 512 + sg;
  const int lw = w * 512;

#define STAGE_A(kt, h, b)                                                   \
  { const unsigned short* g_ = gA + (size_t)(h) * 128 * lda + (kt) * 64;    \
    unsigned short* l_ = &pool[(b) * 16384 + (h) * 8192 + lw];              \
    gl16(g_, l_); gl16(g_ + (size_t)64 * lda, l_ + 4096); }
#define STAGE_B(kt, h, b)                                                   \
  { const unsigned short* g_ = gB + (size_t)(h) * 128 * 512 + (kt) * 64;    \
    unsigned short* l_ = &pool[32768 + (b) * 16384 + (h) * 8192 + lw];      \
    gl16(g_, l_); gl16(g_ + (size_t)64 * 512, l_ + 4096); }

  const int fr = lane & 15;
  const int fg = lane >> 4;
  const int fx = lane & 7;
  auto readA = [&](int b, int mi, int kf) -> bf16x8 {
    return *reinterpret_cast<const bf16x8*>(
        &pool[(b) * 16384 + (wm * 128 + mi * 16 + fr) * 64 +
              ((((kf << 2) + fg) ^ fx) << 3)]);
  };
  auto readB = [&](int b, int ni, int kf) -> bf16x8 {
    return *reinterpret_cast<const bf16x8*>(
        &pool[32768 + (b) * 16384 + (wn * 64 + ni * 16 + fr) * 64 +
              ((((kf << 2) + fg) ^ fx) << 3)]);
  };

  f32x4 acc[8][4];
#pragma unroll
  for (int i = 0; i < 8; ++i)
#pragma unroll
    for (int j = 0; j < 4; ++j) acc[i][j] = (f32x4){0.f, 0.f, 0.f, 0.f};
  bf16x8 bfr[4][2];

#define PHASE(b, q, READB, STAGES, VM)                                       \
  {                                                                          \
    bf16x8 a0_ = readA(b, 2 * (q), 0), a1_ = readA(b, 2 * (q), 1);           \
    bf16x8 a2_ = readA(b, 2 * (q) + 1, 0), a3_ = readA(b, 2 * (q) + 1, 1);   \
    if (READB) {                                                             \
      _Pragma("unroll") for (int ni = 0; ni < 4; ++ni) {                     \
        bfr[ni][0] = readB(b, ni, 0);                                        \
        bfr[ni][1] = readB(b, ni, 1);                                        \
      }                                                                      \
    }                                                                        \
    STAGES;                                                                  \
    if ((VM) == 4) asm volatile("s_waitcnt vmcnt(4)" ::: "memory");          \
    if ((VM) == 0) asm volatile("s_waitcnt vmcnt(0)" ::: "memory");          \
    __builtin_amdgcn_s_barrier();                                            \
    asm volatile("s_waitcnt lgkmcnt(0)" ::: "memory");                       \
    __builtin_amdgcn_sched_barrier(0);                                       \
    __builtin_amdgcn_s_setprio(1);                                           \
    _Pragma("unroll") for (int ni = 0; ni < 4; ++ni) {                       \
      acc[2 * (q)][ni] = __builtin_amdgcn_mfma_f32_16x16x32_bf16(            \
          a0_, bfr[ni][0], acc[2 * (q)][ni], 0, 0, 0);                       \
      acc[2 * (q) + 1][ni] = __builtin_amdgcn_mfma_f32_16x16x32_bf16(        \
          a2_, bfr[ni][0], acc[2 * (q) + 1][ni], 0, 0, 0);                   \
    }                                                                        \
    _Pragma("unroll") for (int ni = 0; ni < 4; ++ni) {                       \
      acc[2 * (q)][ni] = __builtin_amdgcn_mfma_f32_16x16x32_bf16(            \
          a1_, bfr[ni][1], acc[2 * (q)][ni], 0, 0, 0);                       \
      acc[2 * (q) + 1][ni] = __builtin_amdgcn_mfma_f32_16x16x32_bf16(        \
          a3_, bfr[ni][1], acc[2 * (q) + 1][ni], 0, 0, 0);                   \
    }                                                                        \
    __builtin_amdgcn_s_setprio(0);                                           \
    __builtin_amdgcn_s_barrier();                                            \
  }

  STAGE_B(0, 0, 0); STAGE_B(0, 1, 0);
  STAGE_A(0, 0, 0); STAGE_A(0, 1, 0);
  STAGE_B(1, 0, 1); STAGE_B(1, 1, 1);
  asm volatile("s_waitcnt vmcnt(4)" ::: "memory");
  __builtin_amdgcn_s_barrier();

#pragma unroll
  for (int i = 0; i < 4; ++i) {
    const bool s2 = (i < 3);
    const int vmA = s2 ? 4 : 0;
    const int vmB = s2 ? 4 : 0;
    PHASE(0, 0, true,  { STAGE_A(2 * i + 1, 0, 1) }, -1);
    PHASE(0, 1, false, { STAGE_A(2 * i + 1, 1, 1) if (s2) STAGE_B(2 * i + 2, 0, 0) }, -1);
    PHASE(0, 2, false, { if (s2) STAGE_B(2 * i + 2, 1, 0) }, -1);
    PHASE(0, 3, false, {}, vmA);
    PHASE(1, 0, true,  { if (s2) STAGE_A(2 * i + 2, 0, 0) }, -1);
    PHASE(1, 1, false, { if (s2) STAGE_A(2 * i + 2, 1, 0) }, -1);
    PHASE(1, 2, false, { if (s2) STAGE_B(2 * i + 3, 0, 1) }, -1);
    PHASE(1, 3, false, { if (s2) STAGE_B(2 * i + 3, 1, 1) }, vmB);
  }
#undef PHASE
#undef STAGE_A
#undef STAGE_B

  // ---- coalesced epilogue via LDS staging (R4/R11-verified) ----
  __syncthreads();
  if constexpr (sizeof(CT) == 2) {
#pragma unroll
    for (int ni = 0; ni < 4; ++ni) {
      int cl = wn * 64 + ni * 16 + fr;
      float bc = bias[n0 + cl];
#pragma unroll
      for (int mi = 0; mi < 8; ++mi) {
        int rl = wm * 128 + mi * 16 + fg * 4;
#pragma unroll
        for (int r = 0; r < 4; ++r)
          pool[(rl + r) * 258 + cl] = f2bf(acc[mi][ni][r] + bc);
      }
    }
    __syncthreads();
#pragma unroll
    for (int it = 0; it < 16; ++it) {
      int idx = it * 512 + t;
      int row = idx >> 5, c8 = idx & 31;
      u16x8 v = *reinterpret_cast<const u16x8*>(&pool[row * 258 + c8 * 8]);
      *reinterpret_cast<u16x8*>(&C[(size_t)(m0 + row) * ldc + n0 + c8 * 8]) = v;
    }
  } else {
    float* stf = reinterpret_cast<float*>(pool);
#pragma unroll
    for (int h = 0; h < 2; ++h) {
      if (wm == h) {
#pragma unroll
        for (int ni = 0; ni < 4; ++ni) {
          int cl = wn * 64 + ni * 16 + fr;
          float bc = bias[n0 + cl];
#pragma unroll
          for (int mi = 0; mi < 8; ++mi) {
            int rl = mi * 16 + fg * 4;
#pragma unroll
            for (int r = 0; r < 4; ++r)
              stf[(rl + r) * 258 + cl] = acc[mi][ni][r] + bc;
          }
        }
      }
      __syncthreads();
#pragma unroll
      for (int it = 0; it < 16; ++it) {
        int idx = it * 512 + t;
        int row = idx >> 6, c4 = idx & 63;
        f32x4 v = *reinterpret_cast<const f32x4*>(&stf[row * 258 + c4 * 4]);
        *reinterpret_cast<f32x4*>(
            &C[(size_t)(m0 + h * 128 + row) * ldc + n0 + c4 * 4]) = v;
      }
      __syncthreads();
    }
  }
}

// ---------------- MFMA attention, double-buffered head pipeline -----------
// (R11-verified compute.) Block = 256 thr owns 128 rows; wave does 2
// windows. LDS: K 2x8192 | V 2x8192 | ps 1024 = 33792 shorts.
// CHANGE vs R11: raw s_barrier after counted vmcnt(8) (m201 T4 pattern) --
// __syncthreads drains vmcnt(0), stalling on the 8 ctx stores whose only
// reader is the next kernel. vmcnt(8) retires the 8 older gl16 staging
// loads (FIFO), so K/V for head h+1 are LDS-resident at barrier-exit;
// ps-stash LDS ops are same-wave in-order; dbuf stagger unchanged.
__global__ __launch_bounds__(256) void attn2(unsigned short* __restrict__ QKV) {
  __shared__ alignas(16) unsigned short sh[33792];
  const int VS = 16384, PS = 32768;
  const int t = threadIdx.x;
  const int lane = t & 63;
  const int w = t >> 6;
  const int fr = lane & 15, fg = lane >> 4, fx = lane & 7;
  const int sr = lane >> 3;
  const int sgx = ((lane & 7) ^ sr) << 3;
  const int sgl = (lane & 7) << 3;
  const size_t m0r = (size_t)blockIdx.x * 128;

#define SK2(h, b)                                                            \
  _Pragma("unroll") for (int u = 0; u < 4; ++u) {                            \
    const int r0 = u * 32 + w * 8;                                           \
    gl16(QKV + (m0r + r0 + sr) * 1536 + 512 + (h) * 64 + sgx,                \
         &sh[(b) * 8192 + r0 * 64]);                                         \
  }
#define SV2(h, b)                                                            \
  _Pragma("unroll") for (int u = 0; u < 4; ++u) {                            \
    const int r0 = u * 32 + w * 8;                                           \
    gl16(QKV + (m0r + r0 + sr) * 1536 + 1024 + (h) * 64 + sgl,               \
         &sh[VS + (b) * 8192 + r0 * 64]);                                    \
  }

  SK2(0, 0) SV2(0, 0)
  asm volatile("s_waitcnt vmcnt(0)" ::: "memory");
  __syncthreads();

  for (int h = 0; h < 8; ++h) {
    const int b = h & 1;
    u16x8 q[2][2];
#pragma unroll
    for (int ww = 0; ww < 2; ++ww) {
      const int wi = w * 2 + ww;
      const unsigned short* qrow = QKV + (m0r + wi * 16 + fr) * 1536 + h * 64;
      q[ww][0] = *reinterpret_cast<const u16x8*>(qrow + fg * 8);
      q[ww][1] = *reinterpret_cast<const u16x8*>(qrow + 32 + fg * 8);
    }
    if (h < 7) { SK2(h + 1, b ^ 1) SV2(h + 1, b ^ 1) }

#pragma unroll
    for (int ww = 0; ww < 2; ++ww) {
      const int wi = w * 2 + ww;
      f32x4 s = (f32x4){0.f, 0.f, 0.f, 0.f};
      {
        bf16x8 kf_ = *reinterpret_cast<const bf16x8*>(
            &sh[b * 8192 + (wi * 16 + fr) * 64 + ((fg ^ fx) << 3)]);
        s = __builtin_amdgcn_mfma_f32_16x16x32_bf16(
            kf_, __builtin_bit_cast(bf16x8, q[ww][0]), s, 0, 0, 0);
        kf_ = *reinterpret_cast<const bf16x8*>(
            &sh[b * 8192 + (wi * 16 + fr) * 64 + (((4 + fg) ^ fx) << 3)]);
        s = __builtin_amdgcn_mfma_f32_16x16x32_bf16(
            kf_, __builtin_bit_cast(bf16x8, q[ww][1]), s, 0, 0, 0);
      }
      u16x4 pfu;
#pragma unroll
      for (int r = 0; r < 4; ++r)
        pfu[r] = f2bf(1.0f / (1.0f + __expf(-s[r] * 0.125f)));
      *reinterpret_cast<u16x4*>(&sh[PS + w * 256 + fr * 16 + fg * 4]) = pfu;
      u16x8 pbu = (u16x8){0, 0, 0, 0, 0, 0, 0, 0};
      if (fg < 2)
        pbu = *reinterpret_cast<const u16x8*>(&sh[PS + w * 256 + fr * 16 + fg * 8]);
      bf16x8 pb = __builtin_bit_cast(bf16x8, pbu);
#pragma unroll
      for (int dc = 0; dc < 4; ++dc) {
        u16x8 vau;
#pragma unroll
        for (int j = 0; j < 8; ++j)
          vau[j] = sh[VS + b * 8192 + (wi * 16 + (fg & 1) * 8 + j) * 64 + dc * 16 + fr];
        f32x4 c = __builtin_amdgcn_mfma_f32_16x16x32_bf16(
            __builtin_bit_cast(bf16x8, vau), pb, (f32x4){0.f, 0.f, 0.f, 0.f},
            0, 0, 0);
        u16x4 o;
#pragma unroll
        for (int r = 0; r < 4; ++r) o[r] = f2bf(c[r]);
        *reinterpret_cast<u16x4*>(
            &QKV[(m0r + wi * 16 + fr) * 1536 + 1024 + h * 64 + dc * 16 + fg * 4]) = o;
      }
    }
    // counted drain: retire the 8 gl16 staging loads (oldest); the 8 ctx
    // stores (newest) stay in flight across the raw barrier.
    asm volatile("s_waitcnt vmcnt(8)" ::: "memory");
    __builtin_amdgcn_s_barrier();
  }
#undef SK2
#undef SV2
}

// --------------------------------------------------------------------------
extern "C" void kernel_launch(void* const* d_in, const int* in_sizes, int n_in,
                              void* d_out, int out_size, void* d_ws, size_t ws_size,
                              hipStream_t stream) {
  const float* x  = (const float*)d_in[0];
  const float* Wq = (const float*)d_in[1];
  const float* bq = (const float*)d_in[2];
  const float* Wk = (const float*)d_in[3];
  const float* bk = (const float*)d_in[4];
  const float* Wv = (const float*)d_in[5];
  const float* bv = (const float*)d_in[6];
  const float* Wo = (const float*)d_in[7];
  const float* bo = (const float*)d_in[8];
  float* out = (float*)d_out;

  const int M = 65536;
  char* ws = (char*)d_ws;
  unsigned short* WT = (unsigned short*)ws;                  // [2048][512] bf16
  float* biasc = (float*)(ws + (size_t)2048 * 512 * 2);      // [1536]
  const long long prep_bytes = (long long)2048 * 512 * 2 + 8192;

  prep_wt<<<dim3(8, 8, 4), 256, 0, stream>>>(Wq, Wk, Wv, Wo, WT);
  prep_bias<<<6, 256, 0, stream>>>(bq, bk, bv, biasc);

  // per-chunk: Xb rows*512*2 + QKV rows*1536*2 = rows*4096 B
  long long avail = (long long)ws_size - prep_bytes;
  int chunk_rows = 65536;
  while (chunk_rows > 2048 && (long long)chunk_rows * 4096 > avail) chunk_rows >>= 1;
  const int nchunks = M / chunk_rows;

  unsigned short* Xb  = (unsigned short*)(ws + prep_bytes);
  unsigned short* QKV = Xb + (size_t)chunk_rows * 512;

  for (int c = 0; c < nchunks; ++c) {
    const size_t row0 = (size_t)c * chunk_rows;
    convert_x<<<2048, 256, 0, stream>>>(x + row0 * 512, Xb,
                                        (long long)chunk_rows * 64);
    gemm256<unsigned short><<<(chunk_rows / 256) * 6, 512, 0, stream>>>(
        Xb, 512, WT, QKV, 1536, biasc, 6);
    attn2<<<chunk_rows / 128, 256, 0, stream>>>(QKV);
    gemm256<float><<<(chunk_rows / 256) * 2, 512, 0, stream>>>(
        QKV + 1024, 1536, WT + (size_t)1536 * 512, out + row0 * 512, 512, bo, 2);
  }
}